// Round 2
// baseline (36.997 us; speedup 1.0000x reference)
//
#include <hip/hip_runtime.h>
#include <hip/hip_bf16.h>

// YOLO-style detector decode, 3 scales.
// Scale s: input [B=32, C=255=3*85, H, W], H=W in {13,26,52}
// Output row r (global, concatenated over scales) = 6 floats:
//   [conf, x1, y1, x2, y2, cls]  or all-zero if conf <= thresh.
// Row ordering within a scale: ((b*H+h)*W+w)*3 + a  (matches reshape(-1,6)).
//
// Latency-bound kernel (L3-warm dispatches ran at 0.3 TB/s HBM, 51us):
// fix = max out memory-level parallelism: branchless (no conf-dependent
// stall before the 84 remaining loads), argmax unrolled in 16-wide register
// batches, compile-time HW so address math constant-folds.

#define NUM_B 32
#define NUM_CLS 80
#define CH 255

#define R13 (NUM_B * 13 * 13 * 3)             // 16224
#define R26 (NUM_B * 26 * 26 * 3)             // 64896
#define R52 (NUM_B * 52 * 52 * 3)             // 259584
#define CUM13 R13                              // 16224
#define CUM26 (R13 + R26)                      // 81120
#define TOTAL (R13 + R26 + R52)                // 340704

template <int H, int AOFF>
__device__ __forceinline__ void decode_row(
    const float* __restrict__ in,
    const float* __restrict__ anchors,
    float thresh, float step,
    int r,                      // row index within scale
    float* __restrict__ orow)   // 6-float output row (8B-aligned)
{
    constexpr int W  = H;
    constexpr int HW = H * W;

    const int a    = r % 3;
    const int cell = r / 3;
    const int hw   = cell % HW;
    const int b    = cell / HW;

    // base of this (b, anchor) slab; channel stride = HW (compile-time)
    const float* p = in + ((size_t)(b * CH + a * 85)) * HW + hw;

    // issue everything up front; no data-dependent branch before loads
    const float conf = p[0];
    const float tx   = p[1 * HW];
    const float ty   = p[2 * HW];
    const float tw   = p[3 * HW];
    const float th   = p[4 * HW];

    // argmax over 80 classes, first-max-wins (strict >), 16-wide batches
    const float* pc = p + 5 * HW;
    float best = -3.402823466e+38f;
    int   bi   = 0;
    #pragma unroll
    for (int c0 = 0; c0 < NUM_CLS; c0 += 16) {
        float v[16];
        #pragma unroll
        for (int k = 0; k < 16; ++k)
            v[k] = pc[(size_t)(c0 + k) * HW];
        #pragma unroll
        for (int k = 0; k < 16; ++k)
            if (v[k] > best) { best = v[k]; bi = c0 + k; }
    }

    const int wi = hw % W;
    const int hi = hw / W;

    const float cx = ((float)wi + tx) * step;
    const float cy = ((float)hi + ty) * step;
    const float aw = anchors[AOFF + a * 2 + 0] * __expf(tw);
    const float ah = anchors[AOFF + a * 2 + 1] * __expf(th);

    const float x1 = cx - aw * 0.5f;
    const float y1 = cy - ah * 0.5f;
    const float x2 = x1 + aw;
    const float y2 = y1 + ah;

    const bool m = conf > thresh;
    float2* o2 = (float2*)orow;   // tid*24B -> 8B aligned
    o2[0] = m ? make_float2(conf, x1)       : make_float2(0.f, 0.f);
    o2[1] = m ? make_float2(y1, x2)         : make_float2(0.f, 0.f);
    o2[2] = m ? make_float2(y2, (float)bi)  : make_float2(0.f, 0.f);
}

__global__ __launch_bounds__(256) void detector_decode(
    const float* __restrict__ in13,
    const float* __restrict__ in26,
    const float* __restrict__ in52,
    const float* __restrict__ anchors,   // [3,3,2] flat
    float* __restrict__ out)             // [TOTAL, 6] flat
{
    int tid = blockIdx.x * blockDim.x + threadIdx.x;
    if (tid >= TOTAL) return;

    float* orow = out + (size_t)tid * 6;

    if (tid < CUM13) {
        decode_row<13, 0>(in13, anchors, 0.5f, 32.0f, tid, orow);
    } else if (tid < CUM26) {
        decode_row<26, 6>(in26, anchors, 0.5f, 16.0f, tid - CUM13, orow);
    } else {
        decode_row<52, 12>(in52, anchors, 0.9f, 8.0f, tid - CUM26, orow);
    }
}

extern "C" void kernel_launch(void* const* d_in, const int* in_sizes, int n_in,
                              void* d_out, int out_size, void* d_ws, size_t ws_size,
                              hipStream_t stream) {
    const float* in13    = (const float*)d_in[0];
    const float* in26    = (const float*)d_in[1];
    const float* in52    = (const float*)d_in[2];
    const float* anchors = (const float*)d_in[3];
    float* out = (float*)d_out;

    const int threads = 256;
    const int blocks  = (TOTAL + threads - 1) / threads;
    detector_decode<<<blocks, threads, 0, stream>>>(in13, in26, in52, anchors, out);
}

// Round 3
// 29.058 us; speedup vs baseline: 1.2732x; 1.2732x over previous
//
#include <hip/hip_runtime.h>
#include <hip/hip_bf16.h>

// YOLO-style detector decode, 3 scales.
// Scale s: input [B=32, C=255=3*85, H, W], H=W in {13,26,52}
// Output row r (global, concatenated over scales) = 6 floats:
//   [conf, x1, y1, x2, y2, cls]  or all-zero if conf <= thresh.
// Row ordering within a scale: ((b*H+h)*W+w)*3 + a  (matches reshape(-1,6)).
//
// Round 2 lesson: anchor-interleaved thread mapping made every wave-load
// touch 3 distant segments (~7 cache lines/instr) -> miss-queue bound at
// ~2 TB/s even L3-warm. This version: wave = 64 consecutive hw for ONE
// (b, anchor), so every channel load is one contiguous 256B segment, and
// all base addresses are wave-uniform (SGPR).

#define NUM_B 32
#define NUM_CLS 80
#define CH 255

#define R13 (NUM_B * 13 * 13 * 3)             // 16224
#define R26 (NUM_B * 26 * 26 * 3)             // 64896
#define R52 (NUM_B * 52 * 52 * 3)             // 259584
#define CUM13 R13                              // 16224
#define CUM26 (R13 + R26)                      // 81120
#define TOTAL (R13 + R26 + R52)                // 340704

// blocks per scale: (B*3) * ceil(HW/256)
#define NBLK13 (NUM_B * 3 * 1)                 // 96   (169 <= 256)
#define NBLK26 (NUM_B * 3 * 3)                 // 288  (676 -> 3 tiles)
#define NBLK52 (NUM_B * 3 * 11)                // 1056 (2704 -> 11 tiles)

template <int H, int AOFF, int NTILE>
__device__ __forceinline__ void decode_tile(
    const float* __restrict__ in,
    const float* __restrict__ anchors,
    float thresh, float step,
    int idx,                    // block index within scale: (b*3+a)*NTILE + tile
    float* __restrict__ outs)   // output base for this scale (row 0 of scale)
{
    constexpr int W  = H;
    constexpr int HW = H * W;

    const int tile = idx % NTILE;
    const int ba   = idx / NTILE;
    const int a    = ba % 3;      // wave-uniform
    const int b    = ba / 3;      // wave-uniform

    const int hw = tile * 256 + threadIdx.x;
    if (hw >= HW) return;

    // wave-uniform base + per-lane hw: every load below is a contiguous
    // 256B segment per wave.
    const float* p = in + ((size_t)(b * CH + a * 85)) * HW + hw;

    const float conf = p[0];
    const float tx   = p[1 * HW];
    const float ty   = p[2 * HW];
    const float tw   = p[3 * HW];
    const float th   = p[4 * HW];

    // argmax over 80 classes, first-max-wins (strict >), 16-wide batches
    const float* pc = p + 5 * HW;
    float best = -3.402823466e+38f;
    int   bi   = 0;
    #pragma unroll
    for (int c0 = 0; c0 < NUM_CLS; c0 += 16) {
        float v[16];
        #pragma unroll
        for (int k = 0; k < 16; ++k)
            v[k] = pc[(size_t)(c0 + k) * HW];
        #pragma unroll
        for (int k = 0; k < 16; ++k)
            if (v[k] > best) { best = v[k]; bi = c0 + k; }
    }

    const int wi = hw % W;
    const int hi = hw / W;

    const float cx = ((float)wi + tx) * step;
    const float cy = ((float)hi + ty) * step;
    const float aw = anchors[AOFF + a * 2 + 0] * __expf(tw);
    const float ah = anchors[AOFF + a * 2 + 1] * __expf(th);

    const float x1 = cx - aw * 0.5f;
    const float y1 = cy - ah * 0.5f;
    const float x2 = x1 + aw;
    const float y2 = y1 + ah;

    const bool m = conf > thresh;
    float2* o2 = (float2*)(outs + ((size_t)(b * HW + hw) * 3 + a) * 6);
    o2[0] = m ? make_float2(conf, x1)      : make_float2(0.f, 0.f);
    o2[1] = m ? make_float2(y1, x2)        : make_float2(0.f, 0.f);
    o2[2] = m ? make_float2(y2, (float)bi) : make_float2(0.f, 0.f);
}

__global__ __launch_bounds__(256) void detector_decode(
    const float* __restrict__ in13,
    const float* __restrict__ in26,
    const float* __restrict__ in52,
    const float* __restrict__ anchors,   // [3,3,2] flat
    float* __restrict__ out)             // [TOTAL, 6] flat
{
    const int bid = blockIdx.x;
    if (bid < NBLK13) {
        decode_tile<13, 0, 1>(in13, anchors, 0.5f, 32.0f, bid, out);
    } else if (bid < NBLK13 + NBLK26) {
        decode_tile<26, 6, 3>(in26, anchors, 0.5f, 16.0f, bid - NBLK13,
                              out + (size_t)CUM13 * 6);
    } else {
        decode_tile<52, 12, 11>(in52, anchors, 0.9f, 8.0f,
                                bid - (NBLK13 + NBLK26),
                                out + (size_t)CUM26 * 6);
    }
}

extern "C" void kernel_launch(void* const* d_in, const int* in_sizes, int n_in,
                              void* d_out, int out_size, void* d_ws, size_t ws_size,
                              hipStream_t stream) {
    const float* in13    = (const float*)d_in[0];
    const float* in26    = (const float*)d_in[1];
    const float* in52    = (const float*)d_in[2];
    const float* anchors = (const float*)d_in[3];
    float* out = (float*)d_out;

    const int blocks = NBLK13 + NBLK26 + NBLK52;   // 1440
    detector_decode<<<blocks, 256, 0, stream>>>(in13, in26, in52, anchors, out);
}